// Round 1
// 432.900 us; speedup vs baseline: 1.0203x; 1.0203x over previous
//
#include <hip/hip_runtime.h>

// SlideSum: out = sliding_window_sum_3(x) * alpha, with edge replication.
// x: (64, 4096, 256) fp32 -> out same shape.
//
// out[b,l] = (x[b,c-1]+x[b,c]+x[b,c+1])*alpha, c = clamp(l, 1, 4094)
//
// R3 strategy: same sequential-front decomposition as R2, but
//   (1) PLAIN stores instead of __builtin_nontemporal_store. The harness's
//       own fill kernel sustains 6.5 TB/s with plain wave-coalesced stores;
//       NT was the one constant across R1/R2 (both ~440 us despite opposite
//       access patterns) and is the prime suspect for write amplification.
//   (2) 8 rows per wave (32 per block, 8192 blocks): halves the halo
//       re-read (34 rows fetched per 32 produced) and halves launch count.
//   (3) Branch-free fully-unrolled interior path (fixed trip count 8) so
//       the compiler hoists all 10 independent 1-KiB wave-loads up front;
//       batch-edge waves (2 of 512 per batch) take a separate cold path.

#define LL   4096
#define F4   64     // 256 floats = 64 float4 per row
#define RPW  8      // output rows per wave
#define RPB  32     // rows per block (4 waves * 8)

__global__ __launch_bounds__(256) void
slide_sum_kernel(const float4* __restrict__ x,
                 const float* __restrict__ alpha_p,
                 float4* __restrict__ out) {
    const float alpha = *alpha_p;

    const int lane = threadIdx.x & 63;
    const int wave = threadIdx.x >> 6;
    const int b    = blockIdx.x >> 7;                        // 128 blocks per batch
    const int r0   = ((blockIdx.x & 127) << 5) + wave * RPW; // first output row

    const float4* xb = x   + (size_t)b * LL * F4 + lane;
    float4*       ob = out + (size_t)b * LL * F4 + lane;

    if (r0 != 0 && r0 + (RPW - 1) <= 4094) {
        // ---- interior: fixed trip count, branch-free, fully unrolled ----
        float4 s0 = xb[(r0 - 1) * F4];
        float4 s1 = xb[(r0    ) * F4];
        #pragma unroll
        for (int i = 0; i < RPW; ++i) {
            const int l = r0 + i;
            float4 s2 = xb[(l + 1) * F4];
            float4 r;
            r.x = (s0.x + s1.x + s2.x) * alpha;
            r.y = (s0.y + s1.y + s2.y) * alpha;
            r.z = (s0.z + s1.z + s2.z) * alpha;
            r.w = (s0.w + s1.w + s2.w) * alpha;
            ob[l * F4] = r;
            s0 = s1;
            s1 = s2;
        }
    } else {
        // ---- batch-edge waves: first (r0==0) / last (r0==4088) of a batch ----
        const int lstart = (r0 < 1) ? 1 : r0;
        const int lend   = (r0 + RPW - 1 > 4094) ? 4094 : (r0 + RPW - 1);
        float4 s0 = xb[(lstart - 1) * F4];
        float4 s1 = xb[(lstart    ) * F4];
        for (int l = lstart; l <= lend; ++l) {
            float4 s2 = xb[(l + 1) * F4];
            float4 r;
            r.x = (s0.x + s1.x + s2.x) * alpha;
            r.y = (s0.y + s1.y + s2.y) * alpha;
            r.z = (s0.z + s1.z + s2.z) * alpha;
            r.w = (s0.w + s1.w + s2.w) * alpha;
            ob[l * F4] = r;
            if (l == 1)    ob[0] = r;               // replicated row 0
            if (l == 4094) ob[(LL - 1) * F4] = r;   // replicated row 4095
            s0 = s1;
            s1 = s2;
        }
    }
}

extern "C" void kernel_launch(void* const* d_in, const int* in_sizes, int n_in,
                              void* d_out, int out_size, void* d_ws, size_t ws_size,
                              hipStream_t stream) {
    const float4* x       = (const float4*)d_in[0];
    const float*  alpha_p = (const float*)d_in[1];
    float4*       out     = (float4*)d_out;

    const int blocks = 64 * (LL / RPB);   // 64 * 128 = 8192
    slide_sum_kernel<<<blocks, 256, 0, stream>>>(x, alpha_p, out);
}